// Round 17
// baseline (2783.441 us; speedup 1.0000x reference)
//
#include <hip/hip_runtime.h>
#include <hip/hip_bf16.h>
#include <float.h>
#include <math.h>

#define N_PTS 8192
#define KNN_K 20
#define NKP (N_PTS * KNN_K)
#define NSLICE 32

__device__ __forceinline__ float lrelu(float x) { return x > 0.f ? x : 0.2f * x; }

// f64 integer-valued sortable key: key = s*8192 + (8191-ci), s = monotone u32 map
// of d. key < 2^45 -> exact in f64. key desc == (d desc, ci asc). Distinct
// candidates -> distinct keys (no ties). Real keys > 0; empty slot = 0.0.
__device__ __forceinline__ double pack_keyd(float d, int ci) {
    unsigned u = __float_as_uint(d);
    unsigned s = (u & 0x80000000u) ? ~u : (u | 0x80000000u);
    return fma((double)s, 8192.0, (double)(8191 - ci));
}

// ---------------- prep: xT4 [N][4], xx [N] from point [N][3] ----------------
__global__ void prep3_k(const float* __restrict__ point, float* __restrict__ xT4,
                        float* __restrict__ xx) {
    int n = blockIdx.x * 256 + threadIdx.x;
    if (n >= N_PTS) return;
    float a = point[n * 3 + 0], b = point[n * 3 + 1], c = point[n * 3 + 2];
    *(float4*)(xT4 + (size_t)n * 4) = make_float4(a, b, c, 0.f);
    float s = __fmul_rn(a, a);
    s = fmaf(b, b, s);
    s = fmaf(c, c, s);
    xx[n] = s;
}

// ---------------- knn v12: NSLICE=32 -> 512 blocks x 8 waves = 4 waves/SIMD ----------------
// R16 lesson: 512-thread blocks shrank the grid to 256 -> still 2 waves/SIMD.
// Now grid (16,32): 2 blocks/CU (LDS ~69KB steering, R15-verified) x 8 waves
// = 16 waves/CU = 4 waves/SIMD -> hides the quarter-rate f64 insert chain's
// latency bubbles (R16: VALUBusy 66%). Slice=256, single chunk per slice.
// Selection = merge of 32 sorted partials (provably identical); score chain
// BIT-EXACT vs R7-R16.
template <int CP, int UB, int CHUNK, int PADF>
__global__ __launch_bounds__(512) void knn_k(const float* __restrict__ xT,
                                             const float* __restrict__ xx,
                                             double* __restrict__ pk) {
    __shared__ float lds[CHUNK * CP + PADF];  // PADF tail untouched; sizes allocation
    __shared__ float ldsxx[CHUNK];
    int lane = threadIdx.x & 63;
    int w = threadIdx.x >> 6;
    int q = (blockIdx.x * 8 + w) * 64 + lane;
    int s = blockIdx.y;
    const int SLICE = N_PTS / NSLICE;  // 256
    int m0 = s * SLICE;

    float4 qv[CP / 4];
#pragma unroll
    for (int i = 0; i < CP / 4; ++i) qv[i] = *(const float4*)(xT + (size_t)q * CP + 4 * i);
    float xxq = xx[q];

    double K[KNN_K];
#pragma unroll
    for (int j = 0; j < KNN_K; ++j) K[j] = 0.0;

    for (int c0 = m0; c0 < m0 + SLICE; c0 += CHUNK) {
        __syncthreads();
        {
            const float4* src = (const float4*)(xT + (size_t)c0 * CP);
            float4* dst = (float4*)lds;
            for (int i = threadIdx.x; i < CHUNK * CP / 4; i += 512) dst[i] = src[i];
            for (int i = threadIdx.x; i < CHUNK / 4; i += 512)
                ((float4*)ldsxx)[i] = ((const float4*)(xx + c0))[i];
        }
        __syncthreads();
#pragma unroll 1
        for (int ml = 0; ml < CHUNK; ml += UB) {
            double kq[UB];
#pragma unroll
            for (int u = 0; u < UB; ++u) {
                const float* xm = lds + (size_t)(ml + u) * CP;
                float acc = 0.f;
#pragma unroll
                for (int i = 0; i < CP / 4; ++i) {
                    float4 b = *(const float4*)(xm + 4 * i);
                    acc = fmaf(qv[i].x, b.x, acc);
                    acc = fmaf(qv[i].y, b.y, acc);
                    acc = fmaf(qv[i].z, b.z, acc);
                    acc = fmaf(qv[i].w, b.w, acc);
                }
                float d = __fsub_rn(__fsub_rn(__fmul_rn(2.f, acc), xxq), ldsxx[ml + u]);
                kq[u] = pack_keyd(d, c0 + ml + u);
            }
            double kmx = kq[0];
#pragma unroll
            for (int u = 1; u < UB; ++u) kmx = fmax(kmx, kq[u]);
            // batch guard (exact: key==K[19] impossible across distinct candidates)
            if (kmx > K[KNN_K - 1]) {
#pragma unroll
                for (int u = 0; u < UB; ++u) {
                    double key = kq[u];
#pragma unroll
                    for (int j = 0; j < KNN_K; ++j) {
                        double hi = fmax(K[j], key);
                        key = fmin(K[j], key);
                        K[j] = hi;
                    }
                }
            }
        }
    }
    size_t base = ((size_t)s * N_PTS + q) * KNN_K;
#pragma unroll
    for (int j = 0; j < KNN_K; ++j) __builtin_nontemporal_store(K[j], &pk[base + j]);
}

__global__ __launch_bounds__(256) void knn_merge_k(const double* __restrict__ pk,
                                                   int* __restrict__ idx) {
    int n = blockIdx.x * 256 + threadIdx.x;
    if (n >= N_PTS) return;
    double K[KNN_K];
#pragma unroll
    for (int j = 0; j < KNN_K; ++j) K[j] = 0.0;
#pragma unroll 1
    for (int s = 0; s < NSLICE; ++s) {
        size_t base = ((size_t)s * N_PTS + n) * KNN_K;
#pragma unroll 1
        for (int j = 0; j < KNN_K; ++j) {
            double key = __builtin_nontemporal_load(&pk[base + j]);
            if (key > K[KNN_K - 1]) {
#pragma unroll
                for (int t = 0; t < KNN_K; ++t) {
                    double hi = fmax(K[t], key);
                    key = fmin(K[t], key);
                    K[t] = hi;
                }
            } else break;  // partial sorted desc; rest worse
        }
    }
    for (int k = 0; k < KNN_K; ++k) {
        unsigned long long ik = (unsigned long long)K[k];
        idx[(size_t)n * KNN_K + k] = 8191 - (int)(ik & 8191ull);
    }
}

// ---------------- literal edge conv (R7-exact arithmetic; pinned reg budget) ----------------
template <int CIN, int OT>
__global__ __attribute__((amdgpu_waves_per_eu(2, 3))) __launch_bounds__(256)
void conv_lit_k(const float* __restrict__ xT, int XS,
                const int* __restrict__ idx,
                const float* __restrict__ W,
                float* __restrict__ out) {
    int p = blockIdx.x * 256 + threadIdx.x;
    int o0 = blockIdx.y * OT;
    int n = p / KNN_K;
    int j = idx[p];
    float gg[2 * CIN];
    if (CIN == 3) {
        float4 a = *(const float4*)(xT + (size_t)j * XS);
        float4 c = *(const float4*)(xT + (size_t)n * XS);
        gg[0] = __fsub_rn(a.x, c.x); gg[1] = __fsub_rn(a.y, c.y); gg[2] = __fsub_rn(a.z, c.z);
        gg[3] = c.x; gg[4] = c.y; gg[5] = c.z;
    } else {
#pragma unroll
        for (int i = 0; i < CIN; i += 4) {
            float4 a = *(const float4*)(xT + (size_t)j * XS + i);
            float4 c = *(const float4*)(xT + (size_t)n * XS + i);
            gg[i + 0] = __fsub_rn(a.x, c.x);
            gg[i + 1] = __fsub_rn(a.y, c.y);
            gg[i + 2] = __fsub_rn(a.z, c.z);
            gg[i + 3] = __fsub_rn(a.w, c.w);
            gg[CIN + i + 0] = c.x;
            gg[CIN + i + 1] = c.y;
            gg[CIN + i + 2] = c.z;
            gg[CIN + i + 3] = c.w;
        }
    }
#pragma unroll
    for (int t = 0; t < OT; ++t) {
        const float* wr = W + (size_t)(o0 + t) * 2 * CIN;
        float acc = 0.f;
#pragma unroll
        for (int c = 0; c < 2 * CIN; ++c) acc = fmaf(wr[c], gg[c], acc);
        out[(size_t)(o0 + t) * NKP + p] = acc;
    }
}

// ---------------- generic matmul with OPTIONAL fused BN+leaky on the B-read ----------------
__global__ __attribute__((amdgpu_waves_per_eu(2, 4))) __launch_bounds__(256)
void matmul_k(const float* __restrict__ Wa,
              const float* __restrict__ Wb, int ldw,
              const float* __restrict__ bias,
              const float* __restrict__ B,
              const float* __restrict__ nsc, const float* __restrict__ nsh,
              float* __restrict__ out, int C, int M) {
    int m = blockIdx.x * 256 + threadIdx.x;
    int o0 = blockIdx.y * 16;
    float acc[16];
#pragma unroll
    for (int t = 0; t < 16; ++t) acc[t] = bias ? bias[o0 + t] : 0.f;
    for (int c = 0; c < C; ++c) {
        float bv = B[(size_t)c * M + m];
        if (nsc) bv = lrelu(fmaf(nsc[c], bv, nsh[c]));
#pragma unroll
        for (int t = 0; t < 16; ++t) {
            float wv = Wa[(size_t)(o0 + t) * ldw + c];
            if (Wb) wv -= Wb[(size_t)(o0 + t) * ldw + c];
            acc[t] = fmaf(wv, bv, acc[t]);
        }
    }
#pragma unroll
    for (int t = 0; t < 16; ++t) out[(size_t)(o0 + t) * M + m] = acc[t];
}

// ---------------- per-channel sum/sumsq partials (double, R7-exact) ----------------
__global__ void stats_k(const float* __restrict__ X, double* __restrict__ part, int M, int P) {
    int o = blockIdx.y, p = blockIdx.x;
    int chunk = M / P;
    const float* row = X + (size_t)o * M + (size_t)p * chunk;
    double s = 0., s2 = 0.;
    for (int i = threadIdx.x; i < chunk; i += 256) {
        double v = (double)row[i];
        s += v;
        s2 = fma(v, v, s2);
    }
    __shared__ double ls[256], ls2[256];
    ls[threadIdx.x] = s; ls2[threadIdx.x] = s2;
    __syncthreads();
    for (int off = 128; off > 0; off >>= 1) {
        if (threadIdx.x < off) { ls[threadIdx.x] += ls[threadIdx.x + off]; ls2[threadIdx.x] += ls2[threadIdx.x + off]; }
        __syncthreads();
    }
    if (threadIdx.x == 0) {
        part[((size_t)o * P + p) * 2 + 0] = ls[0];
        part[((size_t)o * P + p) * 2 + 1] = ls2[0];
    }
}

__global__ void finalize_k(const double* __restrict__ part, int P, int O, double Md,
                           const float* __restrict__ g, const float* __restrict__ b,
                           float* __restrict__ scale, float* __restrict__ shift) {
    int o = blockIdx.x * 256 + threadIdx.x;
    if (o >= O) return;
    double s = 0., s2 = 0.;
    for (int p = 0; p < P; ++p) {
        s += part[((size_t)o * P + p) * 2 + 0];
        s2 += part[((size_t)o * P + p) * 2 + 1];
    }
    double mean = s / Md;
    double var = s2 / Md - mean * mean;
    double inv = 1.0 / sqrt(var + 1e-5);
    scale[o] = (float)((double)g[o] * inv);
    shift[o] = (float)((double)b[o] - mean * (double)g[o] * inv);
}

// ---------------- affine + leaky + max over k, optional transpose write (R7-exact) ----------------
__global__ void norm_max_k(const float* __restrict__ H, const float* __restrict__ scale,
                           const float* __restrict__ shift, float* __restrict__ xout,
                           float* __restrict__ xT, int writeT) {
    int t = blockIdx.x * 256 + threadIdx.x;  // over 64*N
    int o = t >> 13, n = t & (N_PTS - 1);
    float sc = scale[o], sh = shift[o];
    const float* p = H + (size_t)o * NKP + (size_t)n * KNN_K;
    float mx = -FLT_MAX;
    for (int k = 0; k < KNN_K; ++k) {
        float v = lrelu(fmaf(sc, p[k], sh));
        mx = fmaxf(mx, v);
    }
    xout[(size_t)o * N_PTS + n] = mx;
    if (writeT) xT[(size_t)n * 64 + o] = mx;
}

// ---------------- xx over 64 channels: SINGLE seq-FMA ascending chain (R7-exact) ----------------
__global__ void xx64_k(const float* __restrict__ xT, float* __restrict__ xx) {
    int n = blockIdx.x * 256 + threadIdx.x;
    const float* r = xT + (size_t)n * 64;
    float s = __fmul_rn(r[0], r[0]);
#pragma unroll
    for (int i = 1; i < 64; ++i) s = fmaf(r[i], r[i], s);
    xx[n] = s;
}

// ---------------- per-channel max of affine+leaky (for emax, R7-exact) ----------------
__global__ void emax_k(const float* __restrict__ E, const float* __restrict__ scale,
                       const float* __restrict__ shift, float* __restrict__ emax) {
    int o = blockIdx.x;
    float sc = scale[o], sh = shift[o];
    const float* row = E + (size_t)o * N_PTS;
    float mx = -FLT_MAX;
    for (int i = threadIdx.x; i < N_PTS; i += 256) mx = fmaxf(mx, lrelu(fmaf(sc, row[i], sh)));
    __shared__ float ls[256];
    ls[threadIdx.x] = mx;
    __syncthreads();
    for (int off = 128; off > 0; off >>= 1) {
        if (threadIdx.x < off) ls[threadIdx.x] = fmaxf(ls[threadIdx.x], ls[threadIdx.x + off]);
        __syncthreads();
    }
    if (threadIdx.x == 0) emax[o] = ls[0];
}

// ---------------- c8[o] = sum_{j<1024} W8[o][j] * emax[j] (R7-exact) ----------------
__global__ void c8_k(const float* __restrict__ W8, const float* __restrict__ emax,
                     float* __restrict__ c8) {
    int o = threadIdx.x;  // 256 threads, 1 block
    float acc = 0.f;
    for (int j = 0; j < 1024; ++j) acc = fmaf(W8[(size_t)o * 1216 + j], emax[j], acc);
    c8[o] = acc;
}

// ---------------- final: out[n][o] = sum_c W11[o][c] * bn(h10)[c][n] (fused norm) ----------------
__global__ __attribute__((amdgpu_waves_per_eu(2, 4))) __launch_bounds__(256)
void out_k(const float* __restrict__ W11, const float* __restrict__ H,
           const float* __restrict__ nsc, const float* __restrict__ nsh,
           float* __restrict__ out) {
    int n = blockIdx.x * 256 + threadIdx.x;
    float acc[50];
#pragma unroll
    for (int o = 0; o < 50; ++o) acc[o] = 0.f;
    for (int c = 0; c < 128; ++c) {
        float bv = H[(size_t)c * N_PTS + n];
        bv = lrelu(fmaf(nsc[c], bv, nsh[c]));
#pragma unroll
        for (int o = 0; o < 50; ++o) acc[o] = fmaf(W11[o * 128 + c], bv, acc[o]);
    }
#pragma unroll
    for (int o = 0; o < 50; ++o) out[(size_t)n * 50 + o] = acc[o];
}

extern "C" void kernel_launch(void* const* d_in, const int* in_sizes, int n_in,
                              void* d_out, int out_size, void* d_ws, size_t ws_size,
                              hipStream_t stream) {
    (void)in_sizes; (void)n_in; (void)out_size; (void)ws_size;
    const float* point = (const float*)d_in[0];
    const float* W1 = (const float*)d_in[2];
    const float* W2 = (const float*)d_in[3];
    const float* W3 = (const float*)d_in[4];
    const float* W4 = (const float*)d_in[5];
    const float* W5 = (const float*)d_in[6];
    const float* W6 = (const float*)d_in[7];
    const float* W8 = (const float*)d_in[8];
    const float* W9 = (const float*)d_in[9];
    const float* W10 = (const float*)d_in[10];
    const float* W11 = (const float*)d_in[11];
    const float* G1 = (const float*)d_in[12], *B1 = (const float*)d_in[13];
    const float* G2 = (const float*)d_in[14], *B2 = (const float*)d_in[15];
    const float* G3 = (const float*)d_in[16], *B3 = (const float*)d_in[17];
    const float* G4 = (const float*)d_in[18], *B4 = (const float*)d_in[19];
    const float* G5 = (const float*)d_in[20], *B5 = (const float*)d_in[21];
    const float* G6 = (const float*)d_in[22], *B6 = (const float*)d_in[23];
    const float* G8 = (const float*)d_in[24], *B8 = (const float*)d_in[25];
    const float* G9 = (const float*)d_in[26], *B9 = (const float*)d_in[27];
    const float* G10 = (const float*)d_in[28], *B10 = (const float*)d_in[29];

    char* ws = (char*)d_ws;
    // workspace layout
    float* xT    = (float*)(ws + 0);             // [8192][64] (stage1 uses [8192][4])
    float* xx    = (float*)(ws + 2097152);       // [8192]
    float* cat   = (float*)(ws + 2228224);       // [192][8192] = x1|x2|x3
    int*   idx   = (int*)  (ws + 10616832);      // [8192][20]
    float* scale = (float*)(ws + 11272192);      // [1024]
    float* shift = (float*)(ws + 11276288);      // [1024]
    float* emax  = (float*)(ws + 11280384);      // [1024]
    float* c8    = (float*)(ws + 11284480);      // [256]
    double* part = (double*)(ws + 11288576);     // [1024][32][2]
    float* hA    = (float*)(ws + 11812864);      // [64][163840]  (41.94 MB)
    float* hB    = (float*)(ws + 53755904);      // [64][163840]  (41.94 MB)
    // aliases
    double* pk = (double*)hA;                    // [32][8192][20] f64 = 41,943,040 B (fits hA exactly)
    float* e  = hB;                              // [1024][8192]
    float* h8 = hA;                              // [256][8192]
    float* h9 = (float*)(ws + 11812864 + 8388608);
    float* h10 = (float*)(ws + 11812864 + 16777216);

    float* x1 = cat;
    float* x2 = cat + (size_t)64 * N_PTS;
    float* x3c = cat + (size_t)128 * N_PTS;

    auto stats_fin = [&](const float* X, int O, int M, const float* g, const float* b) {
        int P = (M == NKP) ? 32 : 8;
        stats_k<<<dim3(P, O), 256, 0, stream>>>(X, part, M, P);
        finalize_k<<<dim3((O + 255) / 256), 256, 0, stream>>>(part, P, O, (double)M, g, b, scale, shift);
    };

    // ---------- stage 1 ----------
    prep3_k<<<32, 256, 0, stream>>>(point, xT, xx);
    knn_k<4, 8, 256, 16384><<<dim3(16, 32), 512, 0, stream>>>(xT, xx, pk);
    knn_merge_k<<<32, 256, 0, stream>>>(pk, idx);
    conv_lit_k<3, 16><<<dim3(640, 4), 256, 0, stream>>>(xT, 4, idx, W1, hA);
    stats_fin(hA, 64, NKP, G1, B1);
    matmul_k<<<dim3(640, 4), 256, 0, stream>>>(W2, nullptr, 64, nullptr, hA, scale, shift, hB, 64, NKP);
    stats_fin(hB, 64, NKP, G2, B2);
    norm_max_k<<<2048, 256, 0, stream>>>(hB, scale, shift, x1, xT, 1);
    xx64_k<<<32, 256, 0, stream>>>(xT, xx);

    // ---------- stage 2 ----------
    knn_k<64, 4, 256, 1024><<<dim3(16, 32), 512, 0, stream>>>(xT, xx, pk);
    knn_merge_k<<<32, 256, 0, stream>>>(pk, idx);
    conv_lit_k<64, 8><<<dim3(640, 8), 256, 0, stream>>>(xT, 64, idx, W3, hA);
    stats_fin(hA, 64, NKP, G3, B3);
    matmul_k<<<dim3(640, 4), 256, 0, stream>>>(W4, nullptr, 64, nullptr, hA, scale, shift, hB, 64, NKP);
    stats_fin(hB, 64, NKP, G4, B4);
    norm_max_k<<<2048, 256, 0, stream>>>(hB, scale, shift, x2, xT, 1);
    xx64_k<<<32, 256, 0, stream>>>(xT, xx);

    // ---------- stage 3 ----------
    knn_k<64, 4, 256, 1024><<<dim3(16, 32), 512, 0, stream>>>(xT, xx, pk);
    knn_merge_k<<<32, 256, 0, stream>>>(pk, idx);
    conv_lit_k<64, 8><<<dim3(640, 8), 256, 0, stream>>>(xT, 64, idx, W5, hA);
    stats_fin(hA, 64, NKP, G5, B5);
    norm_max_k<<<2048, 256, 0, stream>>>(hA, scale, shift, x3c, nullptr, 0);

    // ---------- global feature ----------
    matmul_k<<<dim3(32, 64), 256, 0, stream>>>(W6, nullptr, 192, nullptr, cat, nullptr, nullptr, e, 192, N_PTS);
    stats_fin(e, 1024, N_PTS, G6, B6);
    emax_k<<<1024, 256, 0, stream>>>(e, scale, shift, emax);
    c8_k<<<1, 256, 0, stream>>>(W8, emax, c8);

    // ---------- point blocks ----------
    matmul_k<<<dim3(32, 16), 256, 0, stream>>>(W8 + 1024, nullptr, 1216, c8, cat, nullptr, nullptr, h8, 192, N_PTS);
    stats_fin(h8, 256, N_PTS, G8, B8);
    matmul_k<<<dim3(32, 16), 256, 0, stream>>>(W9, nullptr, 256, nullptr, h8, scale, shift, h9, 256, N_PTS);
    stats_fin(h9, 256, N_PTS, G9, B9);
    matmul_k<<<dim3(32, 8), 256, 0, stream>>>(W10, nullptr, 256, nullptr, h9, scale, shift, h10, 256, N_PTS);
    stats_fin(h10, 128, N_PTS, G10, B10);

    out_k<<<32, 256, 0, stream>>>(W11, h10, scale, shift, (float*)d_out);
}

// Round 18
// 2634.742 us; speedup vs baseline: 1.0564x; 1.0564x over previous
//
#include <hip/hip_runtime.h>
#include <hip/hip_bf16.h>
#include <float.h>
#include <math.h>

#define N_PTS 8192
#define KNN_K 20
#define NKP (N_PTS * KNN_K)
#define NSLICE 16

__device__ __forceinline__ float lrelu(float x) { return x > 0.f ? x : 0.2f * x; }

// f64 integer-valued sortable key: key = s*8192 + (8191-ci), s = monotone u32 map
// of d. key < 2^45 -> exact in f64. key desc == (d desc, ci asc). Distinct
// candidates -> distinct keys (no ties). Real keys > 0; empty slot = 0.0.
__device__ __forceinline__ double pack_keyd(float d, int ci) {
    unsigned u = __float_as_uint(d);
    unsigned s = (u & 0x80000000u) ? ~u : (u | 0x80000000u);
    return fma((double)s, 8192.0, (double)(8191 - ci));
}

// ---------------- prep: xT4 [N][4], xx [N] from point [N][3] ----------------
__global__ void prep3_k(const float* __restrict__ point, float* __restrict__ xT4,
                        float* __restrict__ xx) {
    int n = blockIdx.x * 256 + threadIdx.x;
    if (n >= N_PTS) return;
    float a = point[n * 3 + 0], b = point[n * 3 + 1], c = point[n * 3 + 2];
    *(float4*)(xT4 + (size_t)n * 4) = make_float4(a, b, c, 0.f);
    float s = __fmul_rn(a, a);
    s = fmaf(b, b, s);
    s = fmaf(c, c, s);
    xx[n] = s;
}

// ---------------- knn (R15-verbatim config = measured best: 2497us total) ----------------
// LDS sized to steer the allocator (R15-verified): CP=64 -> 65KB (2 blocks/CU,
// VGPR budget 256, measured VGPR=112, no spill, 372us); CP=4 -> 51KB (3 blocks/CU).
// Single-K f64 max/min insert; batch guard exact. Score chain BIT-EXACT R7-R17.
// grid (32,16), 256 threads: q = (bx*4+w)*64+lane, slice = 512 candidates.
template <int CP, int UB, int CHUNK, int PADF>
__global__ __launch_bounds__(256) void knn_k(const float* __restrict__ xT,
                                             const float* __restrict__ xx,
                                             double* __restrict__ pk) {
    __shared__ float lds[CHUNK * CP + PADF];  // PADF tail untouched; sizes allocation
    __shared__ float ldsxx[CHUNK];
    int lane = threadIdx.x & 63;
    int w = threadIdx.x >> 6;
    int q = (blockIdx.x * 4 + w) * 64 + lane;
    int s = blockIdx.y;
    const int SLICE = N_PTS / NSLICE;  // 512
    int m0 = s * SLICE;

    float4 qv[CP / 4];
#pragma unroll
    for (int i = 0; i < CP / 4; ++i) qv[i] = *(const float4*)(xT + (size_t)q * CP + 4 * i);
    float xxq = xx[q];

    double K[KNN_K];
#pragma unroll
    for (int j = 0; j < KNN_K; ++j) K[j] = 0.0;

    for (int c0 = m0; c0 < m0 + SLICE; c0 += CHUNK) {
        __syncthreads();
        {
            const float4* src = (const float4*)(xT + (size_t)c0 * CP);
            float4* dst = (float4*)lds;
            for (int i = threadIdx.x; i < CHUNK * CP / 4; i += 256) dst[i] = src[i];
            for (int i = threadIdx.x; i < CHUNK / 4; i += 256)
                ((float4*)ldsxx)[i] = ((const float4*)(xx + c0))[i];
        }
        __syncthreads();
#pragma unroll 1
        for (int ml = 0; ml < CHUNK; ml += UB) {
            double kq[UB];
#pragma unroll
            for (int u = 0; u < UB; ++u) {
                const float* xm = lds + (size_t)(ml + u) * CP;
                float acc = 0.f;
#pragma unroll
                for (int i = 0; i < CP / 4; ++i) {
                    float4 b = *(const float4*)(xm + 4 * i);
                    acc = fmaf(qv[i].x, b.x, acc);
                    acc = fmaf(qv[i].y, b.y, acc);
                    acc = fmaf(qv[i].z, b.z, acc);
                    acc = fmaf(qv[i].w, b.w, acc);
                }
                float d = __fsub_rn(__fsub_rn(__fmul_rn(2.f, acc), xxq), ldsxx[ml + u]);
                kq[u] = pack_keyd(d, c0 + ml + u);
            }
            double kmx = kq[0];
#pragma unroll
            for (int u = 1; u < UB; ++u) kmx = fmax(kmx, kq[u]);
            // batch guard (exact: key==K[19] impossible across distinct candidates)
            if (kmx > K[KNN_K - 1]) {
#pragma unroll
                for (int u = 0; u < UB; ++u) {
                    double key = kq[u];
#pragma unroll
                    for (int j = 0; j < KNN_K; ++j) {
                        double hi = fmax(K[j], key);
                        key = fmin(K[j], key);
                        K[j] = hi;
                    }
                }
            }
        }
    }
    size_t base = ((size_t)s * N_PTS + q) * KNN_K;
#pragma unroll
    for (int j = 0; j < KNN_K; ++j) __builtin_nontemporal_store(K[j], &pk[base + j]);
}

__global__ __launch_bounds__(256) void knn_merge_k(const double* __restrict__ pk,
                                                   int* __restrict__ idx) {
    int n = blockIdx.x * 256 + threadIdx.x;
    if (n >= N_PTS) return;
    double K[KNN_K];
#pragma unroll
    for (int j = 0; j < KNN_K; ++j) K[j] = 0.0;
#pragma unroll 1
    for (int s = 0; s < NSLICE; ++s) {
        size_t base = ((size_t)s * N_PTS + n) * KNN_K;
#pragma unroll 1
        for (int j = 0; j < KNN_K; ++j) {
            double key = __builtin_nontemporal_load(&pk[base + j]);
            if (key > K[KNN_K - 1]) {
#pragma unroll
                for (int t = 0; t < KNN_K; ++t) {
                    double hi = fmax(K[t], key);
                    key = fmin(K[t], key);
                    K[t] = hi;
                }
            } else break;  // partial sorted desc; rest worse
        }
    }
    for (int k = 0; k < KNN_K; ++k) {
        unsigned long long ik = (unsigned long long)K[k];
        idx[(size_t)n * KNN_K + k] = 8191 - (int)(ik & 8191ull);
    }
}

// ---------------- literal edge conv (R7-exact arithmetic; pinned reg budget) ----------------
template <int CIN, int OT>
__global__ __attribute__((amdgpu_waves_per_eu(2, 3))) __launch_bounds__(256)
void conv_lit_k(const float* __restrict__ xT, int XS,
                const int* __restrict__ idx,
                const float* __restrict__ W,
                float* __restrict__ out) {
    int p = blockIdx.x * 256 + threadIdx.x;
    int o0 = blockIdx.y * OT;
    int n = p / KNN_K;
    int j = idx[p];
    float gg[2 * CIN];
    if (CIN == 3) {
        float4 a = *(const float4*)(xT + (size_t)j * XS);
        float4 c = *(const float4*)(xT + (size_t)n * XS);
        gg[0] = __fsub_rn(a.x, c.x); gg[1] = __fsub_rn(a.y, c.y); gg[2] = __fsub_rn(a.z, c.z);
        gg[3] = c.x; gg[4] = c.y; gg[5] = c.z;
    } else {
#pragma unroll
        for (int i = 0; i < CIN; i += 4) {
            float4 a = *(const float4*)(xT + (size_t)j * XS + i);
            float4 c = *(const float4*)(xT + (size_t)n * XS + i);
            gg[i + 0] = __fsub_rn(a.x, c.x);
            gg[i + 1] = __fsub_rn(a.y, c.y);
            gg[i + 2] = __fsub_rn(a.z, c.z);
            gg[i + 3] = __fsub_rn(a.w, c.w);
            gg[CIN + i + 0] = c.x;
            gg[CIN + i + 1] = c.y;
            gg[CIN + i + 2] = c.z;
            gg[CIN + i + 3] = c.w;
        }
    }
#pragma unroll
    for (int t = 0; t < OT; ++t) {
        const float* wr = W + (size_t)(o0 + t) * 2 * CIN;
        float acc = 0.f;
#pragma unroll
        for (int c = 0; c < 2 * CIN; ++c) acc = fmaf(wr[c], gg[c], acc);
        out[(size_t)(o0 + t) * NKP + p] = acc;
    }
}

// ---------------- generic matmul with OPTIONAL fused BN+leaky on the B-read ----------------
// bv = lrelu(fmaf(nsc[c], raw, nsh[c])) — identical instruction sequence to the
// former separate norm_leaky_k pass (bit-exact), applied at read time.
__global__ __attribute__((amdgpu_waves_per_eu(2, 4))) __launch_bounds__(256)
void matmul_k(const float* __restrict__ Wa,
              const float* __restrict__ Wb, int ldw,
              const float* __restrict__ bias,
              const float* __restrict__ B,
              const float* __restrict__ nsc, const float* __restrict__ nsh,
              float* __restrict__ out, int C, int M) {
    int m = blockIdx.x * 256 + threadIdx.x;
    int o0 = blockIdx.y * 16;
    float acc[16];
#pragma unroll
    for (int t = 0; t < 16; ++t) acc[t] = bias ? bias[o0 + t] : 0.f;
    for (int c = 0; c < C; ++c) {
        float bv = B[(size_t)c * M + m];
        if (nsc) bv = lrelu(fmaf(nsc[c], bv, nsh[c]));
#pragma unroll
        for (int t = 0; t < 16; ++t) {
            float wv = Wa[(size_t)(o0 + t) * ldw + c];
            if (Wb) wv -= Wb[(size_t)(o0 + t) * ldw + c];
            acc[t] = fmaf(wv, bv, acc[t]);
        }
    }
#pragma unroll
    for (int t = 0; t < 16; ++t) out[(size_t)(o0 + t) * M + m] = acc[t];
}

// ---------------- per-channel sum/sumsq partials (double, R7-exact) ----------------
__global__ void stats_k(const float* __restrict__ X, double* __restrict__ part, int M, int P) {
    int o = blockIdx.y, p = blockIdx.x;
    int chunk = M / P;
    const float* row = X + (size_t)o * M + (size_t)p * chunk;
    double s = 0., s2 = 0.;
    for (int i = threadIdx.x; i < chunk; i += 256) {
        double v = (double)row[i];
        s += v;
        s2 = fma(v, v, s2);
    }
    __shared__ double ls[256], ls2[256];
    ls[threadIdx.x] = s; ls2[threadIdx.x] = s2;
    __syncthreads();
    for (int off = 128; off > 0; off >>= 1) {
        if (threadIdx.x < off) { ls[threadIdx.x] += ls[threadIdx.x + off]; ls2[threadIdx.x] += ls2[threadIdx.x + off]; }
        __syncthreads();
    }
    if (threadIdx.x == 0) {
        part[((size_t)o * P + p) * 2 + 0] = ls[0];
        part[((size_t)o * P + p) * 2 + 1] = ls2[0];
    }
}

__global__ void finalize_k(const double* __restrict__ part, int P, int O, double Md,
                           const float* __restrict__ g, const float* __restrict__ b,
                           float* __restrict__ scale, float* __restrict__ shift) {
    int o = blockIdx.x * 256 + threadIdx.x;
    if (o >= O) return;
    double s = 0., s2 = 0.;
    for (int p = 0; p < P; ++p) {
        s += part[((size_t)o * P + p) * 2 + 0];
        s2 += part[((size_t)o * P + p) * 2 + 1];
    }
    double mean = s / Md;
    double var = s2 / Md - mean * mean;
    double inv = 1.0 / sqrt(var + 1e-5);
    scale[o] = (float)((double)g[o] * inv);
    shift[o] = (float)((double)b[o] - mean * (double)g[o] * inv);
}

// ---------------- affine + leaky + max over k, optional transpose write (R7-exact) ----------------
__global__ void norm_max_k(const float* __restrict__ H, const float* __restrict__ scale,
                           const float* __restrict__ shift, float* __restrict__ xout,
                           float* __restrict__ xT, int writeT) {
    int t = blockIdx.x * 256 + threadIdx.x;  // over 64*N
    int o = t >> 13, n = t & (N_PTS - 1);
    float sc = scale[o], sh = shift[o];
    const float* p = H + (size_t)o * NKP + (size_t)n * KNN_K;
    float mx = -FLT_MAX;
    for (int k = 0; k < KNN_K; ++k) {
        float v = lrelu(fmaf(sc, p[k], sh));
        mx = fmaxf(mx, v);
    }
    xout[(size_t)o * N_PTS + n] = mx;
    if (writeT) xT[(size_t)n * 64 + o] = mx;
}

// ---------------- xx over 64 channels: SINGLE seq-FMA ascending chain (R7-exact) ----------------
__global__ void xx64_k(const float* __restrict__ xT, float* __restrict__ xx) {
    int n = blockIdx.x * 256 + threadIdx.x;
    const float* r = xT + (size_t)n * 64;
    float s = __fmul_rn(r[0], r[0]);
#pragma unroll
    for (int i = 1; i < 64; ++i) s = fmaf(r[i], r[i], s);
    xx[n] = s;
}

// ---------------- per-channel max of affine+leaky (for emax, R7-exact) ----------------
__global__ void emax_k(const float* __restrict__ E, const float* __restrict__ scale,
                       const float* __restrict__ shift, float* __restrict__ emax) {
    int o = blockIdx.x;
    float sc = scale[o], sh = shift[o];
    const float* row = E + (size_t)o * N_PTS;
    float mx = -FLT_MAX;
    for (int i = threadIdx.x; i < N_PTS; i += 256) mx = fmaxf(mx, lrelu(fmaf(sc, row[i], sh)));
    __shared__ float ls[256];
    ls[threadIdx.x] = mx;
    __syncthreads();
    for (int off = 128; off > 0; off >>= 1) {
        if (threadIdx.x < off) ls[threadIdx.x] = fmaxf(ls[threadIdx.x], ls[threadIdx.x + off]);
        __syncthreads();
    }
    if (threadIdx.x == 0) emax[o] = ls[0];
}

// ---------------- c8[o] = sum_{j<1024} W8[o][j] * emax[j] (R7-exact) ----------------
__global__ void c8_k(const float* __restrict__ W8, const float* __restrict__ emax,
                     float* __restrict__ c8) {
    int o = threadIdx.x;  // 256 threads, 1 block
    float acc = 0.f;
    for (int j = 0; j < 1024; ++j) acc = fmaf(W8[(size_t)o * 1216 + j], emax[j], acc);
    c8[o] = acc;
}

// ---------------- final: out[n][o] = sum_c W11[o][c] * bn(h10)[c][n] (fused norm) ----------------
__global__ __attribute__((amdgpu_waves_per_eu(2, 4))) __launch_bounds__(256)
void out_k(const float* __restrict__ W11, const float* __restrict__ H,
           const float* __restrict__ nsc, const float* __restrict__ nsh,
           float* __restrict__ out) {
    int n = blockIdx.x * 256 + threadIdx.x;
    float acc[50];
#pragma unroll
    for (int o = 0; o < 50; ++o) acc[o] = 0.f;
    for (int c = 0; c < 128; ++c) {
        float bv = H[(size_t)c * N_PTS + n];
        bv = lrelu(fmaf(nsc[c], bv, nsh[c]));
#pragma unroll
        for (int o = 0; o < 50; ++o) acc[o] = fmaf(W11[o * 128 + c], bv, acc[o]);
    }
#pragma unroll
    for (int o = 0; o < 50; ++o) out[(size_t)n * 50 + o] = acc[o];
}

extern "C" void kernel_launch(void* const* d_in, const int* in_sizes, int n_in,
                              void* d_out, int out_size, void* d_ws, size_t ws_size,
                              hipStream_t stream) {
    (void)in_sizes; (void)n_in; (void)out_size; (void)ws_size;
    const float* point = (const float*)d_in[0];
    const float* W1 = (const float*)d_in[2];
    const float* W2 = (const float*)d_in[3];
    const float* W3 = (const float*)d_in[4];
    const float* W4 = (const float*)d_in[5];
    const float* W5 = (const float*)d_in[6];
    const float* W6 = (const float*)d_in[7];
    const float* W8 = (const float*)d_in[8];
    const float* W9 = (const float*)d_in[9];
    const float* W10 = (const float*)d_in[10];
    const float* W11 = (const float*)d_in[11];
    const float* G1 = (const float*)d_in[12], *B1 = (const float*)d_in[13];
    const float* G2 = (const float*)d_in[14], *B2 = (const float*)d_in[15];
    const float* G3 = (const float*)d_in[16], *B3 = (const float*)d_in[17];
    const float* G4 = (const float*)d_in[18], *B4 = (const float*)d_in[19];
    const float* G5 = (const float*)d_in[20], *B5 = (const float*)d_in[21];
    const float* G6 = (const float*)d_in[22], *B6 = (const float*)d_in[23];
    const float* G8 = (const float*)d_in[24], *B8 = (const float*)d_in[25];
    const float* G9 = (const float*)d_in[26], *B9 = (const float*)d_in[27];
    const float* G10 = (const float*)d_in[28], *B10 = (const float*)d_in[29];

    char* ws = (char*)d_ws;
    // workspace layout (R15-identical)
    float* xT    = (float*)(ws + 0);             // [8192][64] (stage1 uses [8192][4])
    float* xx    = (float*)(ws + 2097152);       // [8192]
    float* cat   = (float*)(ws + 2228224);       // [192][8192] = x1|x2|x3
    int*   idx   = (int*)  (ws + 10616832);      // [8192][20]
    float* scale = (float*)(ws + 11272192);      // [1024]
    float* shift = (float*)(ws + 11276288);      // [1024]
    float* emax  = (float*)(ws + 11280384);      // [1024]
    float* c8    = (float*)(ws + 11284480);      // [256]
    double* part = (double*)(ws + 11288576);     // [1024][32][2]
    float* hA    = (float*)(ws + 11812864);      // [64][163840]  (41.94 MB)
    float* hB    = (float*)(ws + 53755904);      // [64][163840]  (41.94 MB)
    // aliases
    double* pk = (double*)hA;                    // [16][8192][20] f64 = 20,971,520 B
    float* e  = hB;                              // [1024][8192]
    float* h8 = hA;                              // [256][8192]
    float* h9 = (float*)(ws + 11812864 + 8388608);
    float* h10 = (float*)(ws + 11812864 + 16777216);

    float* x1 = cat;
    float* x2 = cat + (size_t)64 * N_PTS;
    float* x3c = cat + (size_t)128 * N_PTS;

    auto stats_fin = [&](const float* X, int O, int M, const float* g, const float* b) {
        int P = (M == NKP) ? 32 : 8;
        stats_k<<<dim3(P, O), 256, 0, stream>>>(X, part, M, P);
        finalize_k<<<dim3((O + 255) / 256), 256, 0, stream>>>(part, P, O, (double)M, g, b, scale, shift);
    };

    // ---------- stage 1 ----------
    prep3_k<<<32, 256, 0, stream>>>(point, xT, xx);
    knn_k<4, 8, 512, 10240><<<dim3(32, 16), 256, 0, stream>>>(xT, xx, pk);
    knn_merge_k<<<32, 256, 0, stream>>>(pk, idx);
    conv_lit_k<3, 16><<<dim3(640, 4), 256, 0, stream>>>(xT, 4, idx, W1, hA);
    stats_fin(hA, 64, NKP, G1, B1);
    matmul_k<<<dim3(640, 4), 256, 0, stream>>>(W2, nullptr, 64, nullptr, hA, scale, shift, hB, 64, NKP);
    stats_fin(hB, 64, NKP, G2, B2);
    norm_max_k<<<2048, 256, 0, stream>>>(hB, scale, shift, x1, xT, 1);
    xx64_k<<<32, 256, 0, stream>>>(xT, xx);

    // ---------- stage 2 ----------
    knn_k<64, 4, 256, 0><<<dim3(32, 16), 256, 0, stream>>>(xT, xx, pk);
    knn_merge_k<<<32, 256, 0, stream>>>(pk, idx);
    conv_lit_k<64, 8><<<dim3(640, 8), 256, 0, stream>>>(xT, 64, idx, W3, hA);
    stats_fin(hA, 64, NKP, G3, B3);
    matmul_k<<<dim3(640, 4), 256, 0, stream>>>(W4, nullptr, 64, nullptr, hA, scale, shift, hB, 64, NKP);
    stats_fin(hB, 64, NKP, G4, B4);
    norm_max_k<<<2048, 256, 0, stream>>>(hB, scale, shift, x2, xT, 1);
    xx64_k<<<32, 256, 0, stream>>>(xT, xx);

    // ---------- stage 3 ----------
    knn_k<64, 4, 256, 0><<<dim3(32, 16), 256, 0, stream>>>(xT, xx, pk);
    knn_merge_k<<<32, 256, 0, stream>>>(pk, idx);
    conv_lit_k<64, 8><<<dim3(640, 8), 256, 0, stream>>>(xT, 64, idx, W5, hA);
    stats_fin(hA, 64, NKP, G5, B5);
    norm_max_k<<<2048, 256, 0, stream>>>(hA, scale, shift, x3c, nullptr, 0);

    // ---------- global feature ----------
    matmul_k<<<dim3(32, 64), 256, 0, stream>>>(W6, nullptr, 192, nullptr, cat, nullptr, nullptr, e, 192, N_PTS);
    stats_fin(e, 1024, N_PTS, G6, B6);
    emax_k<<<1024, 256, 0, stream>>>(e, scale, shift, emax);
    c8_k<<<1, 256, 0, stream>>>(W8, emax, c8);

    // ---------- point blocks ----------
    matmul_k<<<dim3(32, 16), 256, 0, stream>>>(W8 + 1024, nullptr, 1216, c8, cat, nullptr, nullptr, h8, 192, N_PTS);
    stats_fin(h8, 256, N_PTS, G8, B8);
    matmul_k<<<dim3(32, 16), 256, 0, stream>>>(W9, nullptr, 256, nullptr, h8, scale, shift, h9, 256, N_PTS);
    stats_fin(h9, 256, N_PTS, G9, B9);
    matmul_k<<<dim3(32, 8), 256, 0, stream>>>(W10, nullptr, 256, nullptr, h9, scale, shift, h10, 256, N_PTS);
    stats_fin(h10, 128, N_PTS, G10, B10);

    out_k<<<32, 256, 0, stream>>>(W11, h10, scale, shift, (float*)d_out);
}

// Round 19
// 2493.670 us; speedup vs baseline: 1.1162x; 1.0566x over previous
//
#include <hip/hip_runtime.h>
#include <hip/hip_bf16.h>
#include <float.h>
#include <math.h>

#define N_PTS 8192
#define KNN_K 20
#define NKP (N_PTS * KNN_K)
#define NSLICE 16

__device__ __forceinline__ float lrelu(float x) { return x > 0.f ? x : 0.2f * x; }

// f64 integer-valued sortable key: key = s*8192 + (8191-ci), s = monotone u32 map
// of d. key < 2^45 -> exact in f64. key desc == (d desc, ci asc). Distinct
// candidates -> distinct keys (no ties). Real keys > 0; empty slot = 0.0.
__device__ __forceinline__ double pack_keyd(float d, int ci) {
    unsigned u = __float_as_uint(d);
    unsigned s = (u & 0x80000000u) ? ~u : (u | 0x80000000u);
    return fma((double)s, 8192.0, (double)(8191 - ci));
}

// ---------------- prep: xT4 [N][4], xx [N] from point [N][3] ----------------
__global__ void prep3_k(const float* __restrict__ point, float* __restrict__ xT4,
                        float* __restrict__ xx) {
    int n = blockIdx.x * 256 + threadIdx.x;
    if (n >= N_PTS) return;
    float a = point[n * 3 + 0], b = point[n * 3 + 1], c = point[n * 3 + 2];
    *(float4*)(xT4 + (size_t)n * 4) = make_float4(a, b, c, 0.f);
    float s = __fmul_rn(a, a);
    s = fmaf(b, b, s);
    s = fmaf(c, c, s);
    xx[n] = s;
}

// ---------------- knn (R15-verbatim = measured best, 2497us total) ----------------
// LDS sized to steer the allocator: CP=64 -> 65KB (2 blocks/CU, VGPR budget 256,
// measured VGPR=112, no spill, 372us); CP=4 -> 50KB (3 blocks/CU). Candidate reads
// are LDS broadcasts; partial stores nontemporal (keep xT L2-resident).
// Single-K f64 max/min insert; batch guard exact. Score chain BIT-EXACT R7-R18.
// grid (32,16), 256 threads: q = (bx*4+w)*64+lane, slice = 512 candidates.
template <int CP, int UB, int CHUNK, int PADF>
__global__ __launch_bounds__(256) void knn_k(const float* __restrict__ xT,
                                             const float* __restrict__ xx,
                                             double* __restrict__ pk) {
    __shared__ float lds[CHUNK * CP + PADF];  // PADF tail untouched; sizes allocation
    __shared__ float ldsxx[CHUNK];
    int lane = threadIdx.x & 63;
    int w = threadIdx.x >> 6;
    int q = (blockIdx.x * 4 + w) * 64 + lane;
    int s = blockIdx.y;
    const int SLICE = N_PTS / NSLICE;  // 512
    int m0 = s * SLICE;

    float4 qv[CP / 4];
#pragma unroll
    for (int i = 0; i < CP / 4; ++i) qv[i] = *(const float4*)(xT + (size_t)q * CP + 4 * i);
    float xxq = xx[q];

    double K[KNN_K];
#pragma unroll
    for (int j = 0; j < KNN_K; ++j) K[j] = 0.0;

    for (int c0 = m0; c0 < m0 + SLICE; c0 += CHUNK) {
        __syncthreads();
        {
            const float4* src = (const float4*)(xT + (size_t)c0 * CP);
            float4* dst = (float4*)lds;
            for (int i = threadIdx.x; i < CHUNK * CP / 4; i += 256) dst[i] = src[i];
            for (int i = threadIdx.x; i < CHUNK / 4; i += 256)
                ((float4*)ldsxx)[i] = ((const float4*)(xx + c0))[i];
        }
        __syncthreads();
#pragma unroll 1
        for (int ml = 0; ml < CHUNK; ml += UB) {
            double kq[UB];
#pragma unroll
            for (int u = 0; u < UB; ++u) {
                const float* xm = lds + (size_t)(ml + u) * CP;
                float acc = 0.f;
#pragma unroll
                for (int i = 0; i < CP / 4; ++i) {
                    float4 b = *(const float4*)(xm + 4 * i);
                    acc = fmaf(qv[i].x, b.x, acc);
                    acc = fmaf(qv[i].y, b.y, acc);
                    acc = fmaf(qv[i].z, b.z, acc);
                    acc = fmaf(qv[i].w, b.w, acc);
                }
                float d = __fsub_rn(__fsub_rn(__fmul_rn(2.f, acc), xxq), ldsxx[ml + u]);
                kq[u] = pack_keyd(d, c0 + ml + u);
            }
            double kmx = kq[0];
#pragma unroll
            for (int u = 1; u < UB; ++u) kmx = fmax(kmx, kq[u]);
            // batch guard (exact: key==K[19] impossible across distinct candidates)
            if (kmx > K[KNN_K - 1]) {
#pragma unroll
                for (int u = 0; u < UB; ++u) {
                    double key = kq[u];
#pragma unroll
                    for (int j = 0; j < KNN_K; ++j) {
                        double hi = fmax(K[j], key);
                        key = fmin(K[j], key);
                        K[j] = hi;
                    }
                }
            }
        }
    }
    size_t base = ((size_t)s * N_PTS + q) * KNN_K;
#pragma unroll
    for (int j = 0; j < KNN_K; ++j) __builtin_nontemporal_store(K[j], &pk[base + j]);
}

__global__ __launch_bounds__(256) void knn_merge_k(const double* __restrict__ pk,
                                                   int* __restrict__ idx) {
    int n = blockIdx.x * 256 + threadIdx.x;
    if (n >= N_PTS) return;
    double K[KNN_K];
#pragma unroll
    for (int j = 0; j < KNN_K; ++j) K[j] = 0.0;
#pragma unroll 1
    for (int s = 0; s < NSLICE; ++s) {
        size_t base = ((size_t)s * N_PTS + n) * KNN_K;
#pragma unroll 1
        for (int j = 0; j < KNN_K; ++j) {
            double key = __builtin_nontemporal_load(&pk[base + j]);
            if (key > K[KNN_K - 1]) {
#pragma unroll
                for (int t = 0; t < KNN_K; ++t) {
                    double hi = fmax(K[t], key);
                    key = fmin(K[t], key);
                    K[t] = hi;
                }
            } else break;  // partial sorted desc; rest worse
        }
    }
    for (int k = 0; k < KNN_K; ++k) {
        unsigned long long ik = (unsigned long long)K[k];
        idx[(size_t)n * KNN_K + k] = 8191 - (int)(ik & 8191ull);
    }
}

// ---------------- literal edge conv (R7-exact arithmetic; pinned reg budget) ----------------
template <int CIN, int OT>
__global__ __attribute__((amdgpu_waves_per_eu(2, 3))) __launch_bounds__(256)
void conv_lit_k(const float* __restrict__ xT, int XS,
                const int* __restrict__ idx,
                const float* __restrict__ W,
                float* __restrict__ out) {
    int p = blockIdx.x * 256 + threadIdx.x;
    int o0 = blockIdx.y * OT;
    int n = p / KNN_K;
    int j = idx[p];
    float gg[2 * CIN];
    if (CIN == 3) {
        float4 a = *(const float4*)(xT + (size_t)j * XS);
        float4 c = *(const float4*)(xT + (size_t)n * XS);
        gg[0] = __fsub_rn(a.x, c.x); gg[1] = __fsub_rn(a.y, c.y); gg[2] = __fsub_rn(a.z, c.z);
        gg[3] = c.x; gg[4] = c.y; gg[5] = c.z;
    } else {
#pragma unroll
        for (int i = 0; i < CIN; i += 4) {
            float4 a = *(const float4*)(xT + (size_t)j * XS + i);
            float4 c = *(const float4*)(xT + (size_t)n * XS + i);
            gg[i + 0] = __fsub_rn(a.x, c.x);
            gg[i + 1] = __fsub_rn(a.y, c.y);
            gg[i + 2] = __fsub_rn(a.z, c.z);
            gg[i + 3] = __fsub_rn(a.w, c.w);
            gg[CIN + i + 0] = c.x;
            gg[CIN + i + 1] = c.y;
            gg[CIN + i + 2] = c.z;
            gg[CIN + i + 3] = c.w;
        }
    }
#pragma unroll
    for (int t = 0; t < OT; ++t) {
        const float* wr = W + (size_t)(o0 + t) * 2 * CIN;
        float acc = 0.f;
#pragma unroll
        for (int c = 0; c < 2 * CIN; ++c) acc = fmaf(wr[c], gg[c], acc);
        out[(size_t)(o0 + t) * NKP + p] = acc;
    }
}

// ---------------- generic matmul (R7-exact arithmetic; pinned reg budget) ----------------
__global__ __attribute__((amdgpu_waves_per_eu(2, 4))) __launch_bounds__(256)
void matmul_k(const float* __restrict__ Wa,
              const float* __restrict__ Wb, int ldw,
              const float* __restrict__ bias,
              const float* __restrict__ B,
              float* __restrict__ out, int C, int M) {
    int m = blockIdx.x * 256 + threadIdx.x;
    int o0 = blockIdx.y * 16;
    float acc[16];
#pragma unroll
    for (int t = 0; t < 16; ++t) acc[t] = bias ? bias[o0 + t] : 0.f;
    for (int c = 0; c < C; ++c) {
        float bv = B[(size_t)c * M + m];
#pragma unroll
        for (int t = 0; t < 16; ++t) {
            float wv = Wa[(size_t)(o0 + t) * ldw + c];
            if (Wb) wv -= Wb[(size_t)(o0 + t) * ldw + c];
            acc[t] = fmaf(wv, bv, acc[t]);
        }
    }
#pragma unroll
    for (int t = 0; t < 16; ++t) out[(size_t)(o0 + t) * M + m] = acc[t];
}

// ---------------- per-channel sum/sumsq partials (double, R7-exact) ----------------
__global__ void stats_k(const float* __restrict__ X, double* __restrict__ part, int M, int P) {
    int o = blockIdx.y, p = blockIdx.x;
    int chunk = M / P;
    const float* row = X + (size_t)o * M + (size_t)p * chunk;
    double s = 0., s2 = 0.;
    for (int i = threadIdx.x; i < chunk; i += 256) {
        double v = (double)row[i];
        s += v;
        s2 = fma(v, v, s2);
    }
    __shared__ double ls[256], ls2[256];
    ls[threadIdx.x] = s; ls2[threadIdx.x] = s2;
    __syncthreads();
    for (int off = 128; off > 0; off >>= 1) {
        if (threadIdx.x < off) { ls[threadIdx.x] += ls[threadIdx.x + off]; ls2[threadIdx.x] += ls2[threadIdx.x + off]; }
        __syncthreads();
    }
    if (threadIdx.x == 0) {
        part[((size_t)o * P + p) * 2 + 0] = ls[0];
        part[((size_t)o * P + p) * 2 + 1] = ls2[0];
    }
}

__global__ void finalize_k(const double* __restrict__ part, int P, int O, double Md,
                           const float* __restrict__ g, const float* __restrict__ b,
                           float* __restrict__ scale, float* __restrict__ shift) {
    int o = blockIdx.x * 256 + threadIdx.x;
    if (o >= O) return;
    double s = 0., s2 = 0.;
    for (int p = 0; p < P; ++p) {
        s += part[((size_t)o * P + p) * 2 + 0];
        s2 += part[((size_t)o * P + p) * 2 + 1];
    }
    double mean = s / Md;
    double var = s2 / Md - mean * mean;
    double inv = 1.0 / sqrt(var + 1e-5);
    scale[o] = (float)((double)g[o] * inv);
    shift[o] = (float)((double)b[o] - mean * (double)g[o] * inv);
}

// ---------------- in-place affine + leaky (R7-exact; cheap coalesced stream) ----------------
__global__ void norm_leaky_k(float* __restrict__ X, const float* __restrict__ scale,
                             const float* __restrict__ shift, int M) {
    int o = blockIdx.y;
    int m = (blockIdx.x * 256 + threadIdx.x) * 4;
    float sc = scale[o], sh = shift[o];
    float4* p = (float4*)(X + (size_t)o * M + m);
    float4 v = *p;
    v.x = lrelu(fmaf(sc, v.x, sh));
    v.y = lrelu(fmaf(sc, v.y, sh));
    v.z = lrelu(fmaf(sc, v.z, sh));
    v.w = lrelu(fmaf(sc, v.w, sh));
    *p = v;
}

// ---------------- affine + leaky + max over k, optional transpose write (R7-exact) ----------------
__global__ void norm_max_k(const float* __restrict__ H, const float* __restrict__ scale,
                           const float* __restrict__ shift, float* __restrict__ xout,
                           float* __restrict__ xT, int writeT) {
    int t = blockIdx.x * 256 + threadIdx.x;  // over 64*N
    int o = t >> 13, n = t & (N_PTS - 1);
    float sc = scale[o], sh = shift[o];
    const float* p = H + (size_t)o * NKP + (size_t)n * KNN_K;
    float mx = -FLT_MAX;
    for (int k = 0; k < KNN_K; ++k) {
        float v = lrelu(fmaf(sc, p[k], sh));
        mx = fmaxf(mx, v);
    }
    xout[(size_t)o * N_PTS + n] = mx;
    if (writeT) xT[(size_t)n * 64 + o] = mx;
}

// ---------------- xx over 64 channels: SINGLE seq-FMA ascending chain (R7-exact) ----------------
__global__ void xx64_k(const float* __restrict__ xT, float* __restrict__ xx) {
    int n = blockIdx.x * 256 + threadIdx.x;
    const float* r = xT + (size_t)n * 64;
    float s = __fmul_rn(r[0], r[0]);
#pragma unroll
    for (int i = 1; i < 64; ++i) s = fmaf(r[i], r[i], s);
    xx[n] = s;
}

// ---------------- per-channel max of affine+leaky (for emax, R7-exact) ----------------
__global__ void emax_k(const float* __restrict__ E, const float* __restrict__ scale,
                       const float* __restrict__ shift, float* __restrict__ emax) {
    int o = blockIdx.x;
    float sc = scale[o], sh = shift[o];
    const float* row = E + (size_t)o * N_PTS;
    float mx = -FLT_MAX;
    for (int i = threadIdx.x; i < N_PTS; i += 256) mx = fmaxf(mx, lrelu(fmaf(sc, row[i], sh)));
    __shared__ float ls[256];
    ls[threadIdx.x] = mx;
    __syncthreads();
    for (int off = 128; off > 0; off >>= 1) {
        if (threadIdx.x < off) ls[threadIdx.x] = fmaxf(ls[threadIdx.x], ls[threadIdx.x + off]);
        __syncthreads();
    }
    if (threadIdx.x == 0) emax[o] = ls[0];
}

// ---------------- c8[o] = sum_{j<1024} W8[o][j] * emax[j] (R7-exact) ----------------
__global__ void c8_k(const float* __restrict__ W8, const float* __restrict__ emax,
                     float* __restrict__ c8) {
    int o = threadIdx.x;  // 256 threads, 1 block
    float acc = 0.f;
    for (int j = 0; j < 1024; ++j) acc = fmaf(W8[(size_t)o * 1216 + j], emax[j], acc);
    c8[o] = acc;
}

// ---------------- final: out[n][o] = sum_c W11[o][c] * h10[c][n] (R7-exact; pinned) ----------------
__global__ __attribute__((amdgpu_waves_per_eu(2, 4))) __launch_bounds__(256)
void out_k(const float* __restrict__ W11,
           const float* __restrict__ H, float* __restrict__ out) {
    int n = blockIdx.x * 256 + threadIdx.x;
    float acc[50];
#pragma unroll
    for (int o = 0; o < 50; ++o) acc[o] = 0.f;
    for (int c = 0; c < 128; ++c) {
        float bv = H[(size_t)c * N_PTS + n];
#pragma unroll
        for (int o = 0; o < 50; ++o) acc[o] = fmaf(W11[o * 128 + c], bv, acc[o]);
    }
#pragma unroll
    for (int o = 0; o < 50; ++o) out[(size_t)n * 50 + o] = acc[o];
}

extern "C" void kernel_launch(void* const* d_in, const int* in_sizes, int n_in,
                              void* d_out, int out_size, void* d_ws, size_t ws_size,
                              hipStream_t stream) {
    (void)in_sizes; (void)n_in; (void)out_size; (void)ws_size;
    const float* point = (const float*)d_in[0];
    const float* W1 = (const float*)d_in[2];
    const float* W2 = (const float*)d_in[3];
    const float* W3 = (const float*)d_in[4];
    const float* W4 = (const float*)d_in[5];
    const float* W5 = (const float*)d_in[6];
    const float* W6 = (const float*)d_in[7];
    const float* W8 = (const float*)d_in[8];
    const float* W9 = (const float*)d_in[9];
    const float* W10 = (const float*)d_in[10];
    const float* W11 = (const float*)d_in[11];
    const float* G1 = (const float*)d_in[12], *B1 = (const float*)d_in[13];
    const float* G2 = (const float*)d_in[14], *B2 = (const float*)d_in[15];
    const float* G3 = (const float*)d_in[16], *B3 = (const float*)d_in[17];
    const float* G4 = (const float*)d_in[18], *B4 = (const float*)d_in[19];
    const float* G5 = (const float*)d_in[20], *B5 = (const float*)d_in[21];
    const float* G6 = (const float*)d_in[22], *B6 = (const float*)d_in[23];
    const float* G8 = (const float*)d_in[24], *B8 = (const float*)d_in[25];
    const float* G9 = (const float*)d_in[26], *B9 = (const float*)d_in[27];
    const float* G10 = (const float*)d_in[28], *B10 = (const float*)d_in[29];

    char* ws = (char*)d_ws;
    // workspace layout (R15-identical)
    float* xT    = (float*)(ws + 0);             // [8192][64] (stage1 uses [8192][4])
    float* xx    = (float*)(ws + 2097152);       // [8192]
    float* cat   = (float*)(ws + 2228224);       // [192][8192] = x1|x2|x3
    int*   idx   = (int*)  (ws + 10616832);      // [8192][20]
    float* scale = (float*)(ws + 11272192);      // [1024]
    float* shift = (float*)(ws + 11276288);      // [1024]
    float* emax  = (float*)(ws + 11280384);      // [1024]
    float* c8    = (float*)(ws + 11284480);      // [256]
    double* part = (double*)(ws + 11288576);     // [1024][32][2]
    float* hA    = (float*)(ws + 11812864);      // [64][163840]  (41.94 MB)
    float* hB    = (float*)(ws + 53755904);      // [64][163840]  (41.94 MB)
    // aliases
    double* pk = (double*)hA;                    // [16][8192][20] f64 = 20,971,520 B
    float* e  = hB;                              // [1024][8192]
    float* h8 = hA;                              // [256][8192]
    float* h9 = (float*)(ws + 11812864 + 8388608);
    float* h10 = (float*)(ws + 11812864 + 16777216);

    float* x1 = cat;
    float* x2 = cat + (size_t)64 * N_PTS;
    float* x3c = cat + (size_t)128 * N_PTS;

    auto stats_fin = [&](const float* X, int O, int M, const float* g, const float* b) {
        int P = (M == NKP) ? 32 : 8;
        stats_k<<<dim3(P, O), 256, 0, stream>>>(X, part, M, P);
        finalize_k<<<dim3((O + 255) / 256), 256, 0, stream>>>(part, P, O, (double)M, g, b, scale, shift);
    };

    // ---------- stage 1 ----------
    prep3_k<<<32, 256, 0, stream>>>(point, xT, xx);
    knn_k<4, 8, 512, 10240><<<dim3(32, 16), 256, 0, stream>>>(xT, xx, pk);
    knn_merge_k<<<32, 256, 0, stream>>>(pk, idx);
    conv_lit_k<3, 16><<<dim3(640, 4), 256, 0, stream>>>(xT, 4, idx, W1, hA);
    stats_fin(hA, 64, NKP, G1, B1);
    norm_leaky_k<<<dim3(NKP / 1024, 64), 256, 0, stream>>>(hA, scale, shift, NKP);
    matmul_k<<<dim3(640, 4), 256, 0, stream>>>(W2, nullptr, 64, nullptr, hA, hB, 64, NKP);
    stats_fin(hB, 64, NKP, G2, B2);
    norm_max_k<<<2048, 256, 0, stream>>>(hB, scale, shift, x1, xT, 1);
    xx64_k<<<32, 256, 0, stream>>>(xT, xx);

    // ---------- stage 2 ----------
    knn_k<64, 4, 256, 0><<<dim3(32, 16), 256, 0, stream>>>(xT, xx, pk);
    knn_merge_k<<<32, 256, 0, stream>>>(pk, idx);
    conv_lit_k<64, 8><<<dim3(640, 8), 256, 0, stream>>>(xT, 64, idx, W3, hA);
    stats_fin(hA, 64, NKP, G3, B3);
    norm_leaky_k<<<dim3(NKP / 1024, 64), 256, 0, stream>>>(hA, scale, shift, NKP);
    matmul_k<<<dim3(640, 4), 256, 0, stream>>>(W4, nullptr, 64, nullptr, hA, hB, 64, NKP);
    stats_fin(hB, 64, NKP, G4, B4);
    norm_max_k<<<2048, 256, 0, stream>>>(hB, scale, shift, x2, xT, 1);
    xx64_k<<<32, 256, 0, stream>>>(xT, xx);

    // ---------- stage 3 ----------
    knn_k<64, 4, 256, 0><<<dim3(32, 16), 256, 0, stream>>>(xT, xx, pk);
    knn_merge_k<<<32, 256, 0, stream>>>(pk, idx);
    conv_lit_k<64, 8><<<dim3(640, 8), 256, 0, stream>>>(xT, 64, idx, W5, hA);
    stats_fin(hA, 64, NKP, G5, B5);
    norm_max_k<<<2048, 256, 0, stream>>>(hA, scale, shift, x3c, nullptr, 0);

    // ---------- global feature ----------
    matmul_k<<<dim3(32, 64), 256, 0, stream>>>(W6, nullptr, 192, nullptr, cat, e, 192, N_PTS);
    stats_fin(e, 1024, N_PTS, G6, B6);
    emax_k<<<1024, 256, 0, stream>>>(e, scale, shift, emax);
    c8_k<<<1, 256, 0, stream>>>(W8, emax, c8);

    // ---------- point blocks ----------
    matmul_k<<<dim3(32, 16), 256, 0, stream>>>(W8 + 1024, nullptr, 1216, c8, cat, h8, 192, N_PTS);
    stats_fin(h8, 256, N_PTS, G8, B8);
    norm_leaky_k<<<dim3(8, 256), 256, 0, stream>>>(h8, scale, shift, N_PTS);
    matmul_k<<<dim3(32, 16), 256, 0, stream>>>(W9, nullptr, 256, nullptr, h8, h9, 256, N_PTS);
    stats_fin(h9, 256, N_PTS, G9, B9);
    norm_leaky_k<<<dim3(8, 256), 256, 0, stream>>>(h9, scale, shift, N_PTS);
    matmul_k<<<dim3(32, 8), 256, 0, stream>>>(W10, nullptr, 256, nullptr, h9, h10, 256, N_PTS);
    stats_fin(h10, 128, N_PTS, G10, B10);
    norm_leaky_k<<<dim3(8, 128), 256, 0, stream>>>(h10, scale, shift, N_PTS);

    out_k<<<32, 256, 0, stream>>>(W11, h10, (float*)d_out);
}